// Round 5
// baseline (1095.253 us; speedup 1.0000x reference)
//
#include <hip/hip_runtime.h>

#define NPIX 9216
#define IMH 96
#define IMW 96
#define NC 21
#define NCH 22          // 21 classes + norm channel
#define NMON 252        // monomials of degree <=5 in 5 vars
#define RAD 15
#define NITER 5
#define MG 11           // monomials per stage1 block
#define NMG 23          // ceil(252/11): 22 groups of 11 + 1 group of 10

// spatial taps exp(-d^2/18), sigma=3
__constant__ float GW[16] = {
    1.0f, 0.945959f, 0.800737f, 0.606531f, 0.411112f, 0.249352f,
    0.135335f, 0.0657285f, 0.0285655f, 0.0111090f, 0.00386592f,
    0.00120386f, 0.000335463f, 8.36523e-05f, 1.86640e-05f, 3.72665e-06f};

// Taylor coeffs of exp(t) = sum a_k t^k (expansion tuned at c=0.52, deg 5)
__constant__ float d_ak[6] = {0.59449500f, 0.59481184f, 0.29588267f,
                              0.10253333f, 0.02f, 0.00833333f};

// ---------------- prep: unary conv + softmax + features + zero M0 ----------------
__global__ __launch_bounds__(256) void prep_kernel(
    const float* __restrict__ img, const float* __restrict__ net_w,
    const float* __restrict__ net_b,
    float* __restrict__ u, float* __restrict__ s, float* __restrict__ f,
    float* __restrict__ M)
{
    __shared__ float wsh[567], bsh[21];
    const int tid = threadIdx.x;
    for (int i = tid; i < 567; i += 256) wsh[i] = net_w[i];
    if (tid < 21) bsh[tid] = net_b[tid];
    __syncthreads();

    const int n = blockIdx.x * 256 + tid;
    const int i = n / IMW, j = n % IMW;

    if (n < 5632) M[n] = 0.f;   // zero M buffer 0 for iteration 0

    float acc[NC];
    #pragma unroll
    for (int o = 0; o < NC; o++) acc[o] = bsh[o];
    for (int ci = 0; ci < 3; ci++)
        for (int ky = 0; ky < 3; ky++)
            for (int kx = 0; kx < 3; kx++) {
                const int ii = i + ky - 1, jj = j + kx - 1;
                float v = 0.f;
                if (ii >= 0 && ii < IMH && jj >= 0 && jj < IMW)
                    v = img[(ci * IMH + ii) * IMW + jj];
                #pragma unroll
                for (int o = 0; o < NC; o++)
                    acc[o] = fmaf(v, wsh[((o * 3 + ci) * 3 + ky) * 3 + kx], acc[o]);
            }

    float mx = acc[0];
    #pragma unroll
    for (int o = 1; o < NC; o++) mx = fmaxf(mx, acc[o]);
    float e[NC], sum = 0.f;
    #pragma unroll
    for (int o = 0; o < NC; o++) { e[o] = __expf(acc[o] - mx); sum += e[o]; }
    const float inv = 1.f / sum;
    #pragma unroll
    for (int o = 0; o < NC; o++) {
        u[(size_t)o * NPIX + n] = acc[o];
        s[(size_t)o * NPIX + n] = e[o] * inv;
    }
    s[(size_t)21 * NPIX + n] = 1.f;

    const float f1 = (float)j * (1.0f / 160.0f);
    const float f2 = (float)i * (1.0f / 160.0f);
    const float f3 = img[0 * NPIX + n] * (1.0f / 3.0f);
    const float f4 = img[1 * NPIX + n] * (1.0f / 3.0f);
    const float f5 = img[2 * NPIX + n] * (1.0f / 3.0f);
    f[0 * NPIX + n] = f1; f[1 * NPIX + n] = f2; f[2 * NPIX + n] = f3;
    f[3 * NPIX + n] = f4; f[4 * NPIX + n] = f5;
    f[5 * NPIX + n] = __expf(-0.5f * (f1*f1 + f2*f2 + f3*f3 + f4*f4 + f5*f5));
}

// ---------------- phik: monomial features phi + gamma table ----------------
__global__ __launch_bounds__(256) void phik_kernel(
    const float* __restrict__ f, float* __restrict__ phi, float* __restrict__ gam)
{
    const int m = blockIdx.x, tid = threadIdx.x;
    // decode lexicographic monomial index -> exponents (block-uniform)
    int e1 = 0, e2 = 0, e3 = 0, e4 = 0, e5 = 0, cnt = 0;
    bool done = false;
    for (int a = 0; a <= 5 && !done; a++)
        for (int b2 = 0; b2 <= 5 - a && !done; b2++)
            for (int c = 0; c <= 5 - a - b2 && !done; c++)
                for (int d = 0; d <= 5 - a - b2 - c && !done; d++) {
                    const int rem = 5 - a - b2 - c - d;
                    if (m - cnt <= rem) {
                        e1 = a; e2 = b2; e3 = c; e4 = d; e5 = m - cnt; done = true;
                    } else cnt += rem + 1;
                }
    if (blockIdx.y == 0 && tid == 0) {
        const float fact[6] = {1.f, 1.f, 2.f, 6.f, 24.f, 120.f};
        const int k = e1 + e2 + e3 + e4 + e5;
        gam[m] = d_ak[k] * fact[k] /
                 (fact[e1] * fact[e2] * fact[e3] * fact[e4] * fact[e5]);
    }
    for (int kk = 0; kk < 9; kk++) {
        const int px = blockIdx.y * 2304 + kk * 256 + tid;
        float p = f[5 * NPIX + px];
        float v;
        v = f[0 * NPIX + px]; for (int q = 0; q < e1; q++) p *= v;
        v = f[1 * NPIX + px]; for (int q = 0; q < e2; q++) p *= v;
        v = f[2 * NPIX + px]; for (int q = 0; q < e3; q++) p *= v;
        v = f[3 * NPIX + px]; for (int q = 0; q < e4; q++) p *= v;
        v = f[4 * NPIX + px]; for (int q = 0; q < e5; q++) p *= v;
        phi[(size_t)m * NPIX + px] = p;
    }
}

// ---------------- kA: stage1 GEMM (LDS-tiled, atomic M) || conv-x ----------------
__global__ __launch_bounds__(256) void kA_kernel(
    const float* __restrict__ s, const float* __restrict__ phi,
    float* __restrict__ sx, float* __restrict__ M)
{
    __shared__ float smem[NCH * 257 + MG * 257];   // 5654 + 2827 floats
    const int bid = blockIdx.x, tid = threadIdx.x;
    if (bid < NMG * 36) {
        const int g = bid / 36, chunk = bid % 36;
        const int m0 = g * MG;
        const int mcnt = (NMON - m0 < MG) ? (NMON - m0) : MG;
        float* s_sh = smem;
        float* p_sh = smem + NCH * 257;
        for (int idx = tid; idx < NCH * 256; idx += 256) {
            const int c = idx >> 8, px = idx & 255;
            s_sh[c * 257 + px] = s[(size_t)c * NPIX + chunk * 256 + px];
        }
        for (int idx = tid; idx < mcnt * 256; idx += 256) {
            const int mm = idx >> 8, px = idx & 255;
            p_sh[mm * 257 + px] = phi[(size_t)(m0 + mm) * NPIX + chunk * 256 + px];
        }
        __syncthreads();
        const int c = tid % NCH, msub = tid / NCH;
        if (msub < mcnt) {
            const float* sr = s_sh + c * 257;
            const float* pr = p_sh + msub * 257;
            float acc = 0.f;
            for (int px = 0; px < 256; px++) acc = fmaf(pr[px], sr[px], acc);
            atomicAdd(&M[(m0 + msub) * NCH + c], acc);
        }
    } else {
        for (int u2 = bid - NMG * 36; u2 < NCH * 36; u2 += 132) {
            const int ch = u2 / 36, pc = u2 % 36;
            const int n = pc * 256 + tid, j = n % IMW;
            const float* row = s + (size_t)ch * NPIX + (n - j);
            float a = GW[0] * row[j];
            #pragma unroll
            for (int d = 1; d <= RAD; d++) {
                const float l = (j - d >= 0) ? row[j - d] : 0.f;
                const float r = (j + d < IMW) ? row[j + d] : 0.f;
                a = fmaf(GW[d], l + r, a);
            }
            sx[(size_t)ch * NPIX + n] = a;
        }
    }
}

// ---------------- kB: conv-y + stage2 + normalize + compat + softmax -------------
__global__ __launch_bounds__(128) void kB_kernel(
    const float* __restrict__ sx, const float* __restrict__ phi,
    const float* __restrict__ M, float* __restrict__ Mnext,
    const float* __restrict__ gam, const float* __restrict__ u,
    const float* __restrict__ sp_w, const float* __restrict__ sp_b,
    const float* __restrict__ bl_w, const float* __restrict__ bl_b,
    const float* __restrict__ comp_w, const float* __restrict__ comp_b,
    float* __restrict__ s, float* __restrict__ out, int write_out)
{
    __shared__ float Msh[NMON * NCH];   // 5544
    __shared__ float gsh[NMON];
    __shared__ float wsh[1386 + 63];
    const int tid = threadIdx.x;
    const int px = blockIdx.x * 128 + tid;

    for (int i = tid; i < NMON * NCH; i += 128) Msh[i] = M[i];
    for (int i = tid; i < NMON; i += 128) gsh[i] = gam[i];
    for (int i = tid; i < 441; i += 128) {
        wsh[i] = sp_w[i]; wsh[441 + i] = bl_w[i]; wsh[882 + i] = comp_w[i];
    }
    if (tid < 21) {
        wsh[1323 + tid] = sp_b[tid]; wsh[1344 + tid] = bl_b[tid];
        wsh[1365 + tid] = comp_b[tid];
    }
    __syncthreads();

    const int i0 = px / IMW;

    // conv-y into registers (spatial filtered result, incl. norm channel)
    float spv[NCH];
    #pragma unroll
    for (int c = 0; c < NCH; c++) {
        const float* plane = sx + (size_t)c * NPIX;
        float a = GW[0] * plane[px];
        #pragma unroll
        for (int d = 1; d <= RAD; d++) {
            const float t = (i0 - d >= 0) ? plane[px - d * IMW] : 0.f;
            const float b = (i0 + d < IMH) ? plane[px + d * IMW] : 0.f;
            a = fmaf(GW[d], t + b, a);
        }
        spv[c] = a;
    }

    // stage2: bl = sum_m gamma_m phi_m(px) * M[m][:]
    float blv[NCH];
    #pragma unroll
    for (int c = 0; c < NCH; c++) blv[c] = 0.f;
    for (int m = 0; m < NMON; m++) {
        const float p = gsh[m] * phi[(size_t)m * NPIX + px];
        const float* Mr = Msh + m * NCH;
        #pragma unroll
        for (int c = 0; c < NCH; c++) blv[c] = fmaf(p, Mr[c], blv[c]);
    }

    const float invS = 1.f / spv[21];
    const float invB = 1.f / blv[21];
    #pragma unroll
    for (int c = 0; c < NC; c++) { spv[c] *= invS; blv[c] *= invB; }

    float mp[NC];
    for (int o = 0; o < NC; o++) {
        float m = wsh[1323 + o] + wsh[1344 + o];
        #pragma unroll
        for (int c = 0; c < NC; c++)
            m += wsh[o * NC + c] * spv[c] + wsh[441 + o * NC + c] * blv[c];
        mp[o] = m;
    }
    float q[NC];
    for (int o = 0; o < NC; o++) {
        float m = wsh[1365 + o];
        #pragma unroll
        for (int c = 0; c < NC; c++) m += wsh[882 + o * NC + c] * mp[c];
        q[o] = u[(size_t)o * NPIX + px] - m;
    }

    float mx = q[0];
    #pragma unroll
    for (int o = 1; o < NC; o++) mx = fmaxf(mx, q[o]);
    float sum = 0.f;
    #pragma unroll
    for (int o = 0; o < NC; o++) { q[o] = __expf(q[o] - mx); sum += q[o]; }
    const float inv = 1.f / sum;
    #pragma unroll
    for (int o = 0; o < NC; o++) {
        const float sv = q[o] * inv;
        s[(size_t)o * NPIX + px] = sv;
        if (write_out) out[(size_t)o * NPIX + px] = sv;
    }

    // zero the OTHER M buffer for the next iteration (race-free: nobody reads it now)
    for (int i2 = blockIdx.x * 128 + tid; i2 < 5632; i2 += 72 * 128) Mnext[i2] = 0.f;
}

extern "C" void kernel_launch(void* const* d_in, const int* in_sizes, int n_in,
                              void* d_out, int out_size, void* d_ws, size_t ws_size,
                              hipStream_t stream) {
    const float* img    = (const float*)d_in[0];
    const float* net_w  = (const float*)d_in[1];
    const float* net_b  = (const float*)d_in[2];
    const float* sp_w   = (const float*)d_in[3];
    const float* sp_b   = (const float*)d_in[4];
    const float* bl_w   = (const float*)d_in[5];
    const float* bl_b   = (const float*)d_in[6];
    const float* comp_w = (const float*)d_in[7];
    const float* comp_b = (const float*)d_in[8];

    float* u   = (float*)d_ws;                  // [22][NPIX] (21 used)
    float* s   = u + (size_t)NCH * NPIX;        // [22][NPIX]
    float* f   = s + (size_t)NCH * NPIX;        // [6][NPIX]
    float* sx  = f + (size_t)6 * NPIX;          // [22][NPIX]
    float* phi = sx + (size_t)NCH * NPIX;       // [252][NPIX]
    float* M   = phi + (size_t)NMON * NPIX;     // [2][5632] double-buffered
    float* gam = M + 2 * 5632;                  // [252] pad 256

    float* out = (float*)d_out;

    prep_kernel<<<dim3(36), dim3(256), 0, stream>>>(img, net_w, net_b, u, s, f, M);
    phik_kernel<<<dim3(252, 4), dim3(256), 0, stream>>>(f, phi, gam);
    for (int it = 0; it < NITER; it++) {
        float* Mc = M + (it & 1) * 5632;
        float* Mn = M + ((it + 1) & 1) * 5632;
        kA_kernel<<<dim3(NMG * 36 + 132), dim3(256), 0, stream>>>(s, phi, sx, Mc);
        kB_kernel<<<dim3(72), dim3(128), 0, stream>>>(
            sx, phi, Mc, Mn, gam, u, sp_w, sp_b, bl_w, bl_b, comp_w, comp_b,
            s, out, it == NITER - 1 ? 1 : 0);
    }
}

// Round 6
// 317.417 us; speedup vs baseline: 3.4505x; 3.4505x over previous
//
#include <hip/hip_runtime.h>

#define NPIX 9216
#define IMH 96
#define IMW 96
#define NC 21
#define NCH 22          // 21 classes + norm channel
#define NMON 252        // monomials of degree <=5 in 5 vars
#define RAD 15
#define NITER 5
#define MG 11           // monomials per stage1 block
#define NMG 23          // ceil(252/11)

// spatial taps exp(-d^2/18), sigma=3
__constant__ float GW[16] = {
    1.0f, 0.945959f, 0.800737f, 0.606531f, 0.411112f, 0.249352f,
    0.135335f, 0.0657285f, 0.0285655f, 0.0111090f, 0.00386592f,
    0.00120386f, 0.000335463f, 8.36523e-05f, 1.86640e-05f, 3.72665e-06f};

// Taylor coeffs of exp(t) = sum a_k t^k (deg 5, tuned at c=0.52)
__constant__ float d_ak[6] = {0.59449500f, 0.59481184f, 0.29588267f,
                              0.10253333f, 0.02f, 0.00833333f};

// ---------------- prep: unary conv + softmax + features + zero M0 ----------------
__global__ __launch_bounds__(256) void prep_kernel(
    const float* __restrict__ img, const float* __restrict__ net_w,
    const float* __restrict__ net_b,
    float* __restrict__ u, float* __restrict__ s, float* __restrict__ f,
    float* __restrict__ M)
{
    __shared__ float wsh[567], bsh[21];
    const int tid = threadIdx.x;
    for (int i = tid; i < 567; i += 256) wsh[i] = net_w[i];
    if (tid < 21) bsh[tid] = net_b[tid];
    __syncthreads();

    const int n = blockIdx.x * 256 + tid;
    const int i = n / IMW, j = n % IMW;

    if (n < 5632) M[n] = 0.f;

    float acc[NC];
    #pragma unroll
    for (int o = 0; o < NC; o++) acc[o] = bsh[o];
    for (int ci = 0; ci < 3; ci++)
        for (int ky = 0; ky < 3; ky++)
            for (int kx = 0; kx < 3; kx++) {
                const int ii = i + ky - 1, jj = j + kx - 1;
                float v = 0.f;
                if (ii >= 0 && ii < IMH && jj >= 0 && jj < IMW)
                    v = img[(ci * IMH + ii) * IMW + jj];
                #pragma unroll
                for (int o = 0; o < NC; o++)
                    acc[o] = fmaf(v, wsh[((o * 3 + ci) * 3 + ky) * 3 + kx], acc[o]);
            }

    float mx = acc[0];
    #pragma unroll
    for (int o = 1; o < NC; o++) mx = fmaxf(mx, acc[o]);
    float e[NC], sum = 0.f;
    #pragma unroll
    for (int o = 0; o < NC; o++) { e[o] = __expf(acc[o] - mx); sum += e[o]; }
    const float inv = 1.f / sum;
    #pragma unroll
    for (int o = 0; o < NC; o++) {
        u[(size_t)o * NPIX + n] = acc[o];
        s[(size_t)o * NPIX + n] = e[o] * inv;
    }
    s[(size_t)21 * NPIX + n] = 1.f;

    const float f1 = (float)j * (1.0f / 160.0f);
    const float f2 = (float)i * (1.0f / 160.0f);
    const float f3 = img[0 * NPIX + n] * (1.0f / 3.0f);
    const float f4 = img[1 * NPIX + n] * (1.0f / 3.0f);
    const float f5 = img[2 * NPIX + n] * (1.0f / 3.0f);
    f[0 * NPIX + n] = f1; f[1 * NPIX + n] = f2; f[2 * NPIX + n] = f3;
    f[3 * NPIX + n] = f4; f[4 * NPIX + n] = f5;
    f[5 * NPIX + n] = __expf(-0.5f * (f1*f1 + f2*f2 + f3*f3 + f4*f4 + f5*f5));
}

// ---------------- phik: monomial features phi + gamma table ----------------
__global__ __launch_bounds__(256) void phik_kernel(
    const float* __restrict__ f, float* __restrict__ phi, float* __restrict__ gam)
{
    const int m = blockIdx.x, tid = threadIdx.x;
    int e1 = 0, e2 = 0, e3 = 0, e4 = 0, e5 = 0, cnt = 0;
    bool done = false;
    for (int a = 0; a <= 5 && !done; a++)
        for (int b2 = 0; b2 <= 5 - a && !done; b2++)
            for (int c = 0; c <= 5 - a - b2 && !done; c++)
                for (int d = 0; d <= 5 - a - b2 - c && !done; d++) {
                    const int rem = 5 - a - b2 - c - d;
                    if (m - cnt <= rem) {
                        e1 = a; e2 = b2; e3 = c; e4 = d; e5 = m - cnt; done = true;
                    } else cnt += rem + 1;
                }
    if (blockIdx.y == 0 && tid == 0) {
        const float fact[6] = {1.f, 1.f, 2.f, 6.f, 24.f, 120.f};
        const int k = e1 + e2 + e3 + e4 + e5;
        gam[m] = d_ak[k] * fact[k] /
                 (fact[e1] * fact[e2] * fact[e3] * fact[e4] * fact[e5]);
    }
    for (int kk = 0; kk < 9; kk++) {
        const int px = blockIdx.y * 2304 + kk * 256 + tid;
        float p = f[5 * NPIX + px];
        float v;
        v = f[0 * NPIX + px]; for (int q = 0; q < e1; q++) p *= v;
        v = f[1 * NPIX + px]; for (int q = 0; q < e2; q++) p *= v;
        v = f[2 * NPIX + px]; for (int q = 0; q < e3; q++) p *= v;
        v = f[3 * NPIX + px]; for (int q = 0; q < e4; q++) p *= v;
        v = f[4 * NPIX + px]; for (int q = 0; q < e5; q++) p *= v;
        phi[(size_t)m * NPIX + px] = p;
    }
}

// ---------------- kA: stage1 GEMM (LDS-tiled, atomic M) || conv-x ----------------
__global__ __launch_bounds__(256) void kA_kernel(
    const float* __restrict__ s, const float* __restrict__ phi,
    float* __restrict__ sx, float* __restrict__ M)
{
    __shared__ float smem[NCH * 257 + MG * 257];
    const int bid = blockIdx.x, tid = threadIdx.x;
    if (bid < NMG * 36) {
        const int g = bid / 36, chunk = bid % 36;
        const int m0 = g * MG;
        const int mcnt = (NMON - m0 < MG) ? (NMON - m0) : MG;
        float* s_sh = smem;
        float* p_sh = smem + NCH * 257;
        for (int idx = tid; idx < NCH * 256; idx += 256) {
            const int c = idx >> 8, px = idx & 255;
            s_sh[c * 257 + px] = s[(size_t)c * NPIX + chunk * 256 + px];
        }
        for (int idx = tid; idx < mcnt * 256; idx += 256) {
            const int mm = idx >> 8, px = idx & 255;
            p_sh[mm * 257 + px] = phi[(size_t)(m0 + mm) * NPIX + chunk * 256 + px];
        }
        __syncthreads();
        const int c = tid % NCH, msub = tid / NCH;
        if (msub < mcnt) {
            const float* sr = s_sh + c * 257;
            const float* pr = p_sh + msub * 257;
            float acc = 0.f;
            for (int px = 0; px < 256; px++) acc = fmaf(pr[px], sr[px], acc);
            atomicAdd(&M[(m0 + msub) * NCH + c], acc);
        }
    } else {
        for (int u2 = bid - NMG * 36; u2 < NCH * 36; u2 += 132) {
            const int ch = u2 / 36, pc = u2 % 36;
            const int n = pc * 256 + tid, j = n % IMW;
            const float* row = s + (size_t)ch * NPIX + (n - j);
            float a = GW[0] * row[j];
            #pragma unroll
            for (int d = 1; d <= RAD; d++) {
                const float l = (j - d >= 0) ? row[j - d] : 0.f;
                const float r = (j + d < IMW) ? row[j + d] : 0.f;
                a = fmaf(GW[d], l + r, a);
            }
            sx[(size_t)ch * NPIX + n] = a;
        }
    }
}

// ---------------- kB1: conv-y -> spo  ||  stage2 partials -> blp ----------------
__global__ __launch_bounds__(256) void kB1_kernel(
    const float* __restrict__ sx, const float* __restrict__ phi,
    const float* __restrict__ M, const float* __restrict__ gam,
    float* __restrict__ spo, float* __restrict__ blp, int nmc, int msz)
{
    const int bid = blockIdx.x, tid = threadIdx.x;
    if (bid < nmc * 36) {
        __shared__ float Msh[NMON * NCH];
        __shared__ float gsh[NMON];
        const int mc = bid / 36, pc = bid % 36;
        const int m0 = mc * msz;
        for (int i2 = tid; i2 < msz * NCH; i2 += 256) Msh[i2] = M[m0 * NCH + i2];
        for (int i2 = tid; i2 < msz; i2 += 256) gsh[i2] = gam[m0 + i2];
        __syncthreads();
        const int px = pc * 256 + tid;
        float acc[NCH];
        #pragma unroll
        for (int c = 0; c < NCH; c++) acc[c] = 0.f;
        for (int mm = 0; mm < msz; mm++) {
            const float p = gsh[mm] * phi[(size_t)(m0 + mm) * NPIX + px];
            #pragma unroll
            for (int c = 0; c < NCH; c++) acc[c] = fmaf(p, Msh[mm * NCH + c], acc[c]);
        }
        #pragma unroll
        for (int c = 0; c < NCH; c++)
            blp[((size_t)mc * NCH + c) * NPIX + px] = acc[c];
    } else {
        const int u2 = bid - nmc * 36;
        const int ch = u2 / 36, pc = u2 % 36;
        const int n = pc * 256 + tid, i = n / IMW;
        const float* plane = sx + (size_t)ch * NPIX;
        float a = GW[0] * plane[n];
        #pragma unroll
        for (int d = 1; d <= RAD; d++) {
            const float t = (i - d >= 0) ? plane[n - d * IMW] : 0.f;
            const float b = (i + d < IMH) ? plane[n + d * IMW] : 0.f;
            a = fmaf(GW[d], t + b, a);
        }
        spo[(size_t)ch * NPIX + n] = a;
    }
}

// ---------------- kB2: combine = normalize + compat + softmax -------------------
__global__ __launch_bounds__(256) void kB2_kernel(
    const float* __restrict__ spo, const float* __restrict__ blp, int nmc,
    const float* __restrict__ u, float* __restrict__ Mnext,
    const float* __restrict__ sp_w, const float* __restrict__ sp_b,
    const float* __restrict__ bl_w, const float* __restrict__ bl_b,
    const float* __restrict__ comp_w, const float* __restrict__ comp_b,
    float* __restrict__ s, float* __restrict__ out, int write_out)
{
    __shared__ float wsh[1386 + 63];
    const int tid = threadIdx.x;
    for (int i = tid; i < 441; i += 256) {
        wsh[i] = sp_w[i]; wsh[441 + i] = bl_w[i]; wsh[882 + i] = comp_w[i];
    }
    if (tid < 21) {
        wsh[1323 + tid] = sp_b[tid]; wsh[1344 + tid] = bl_b[tid];
        wsh[1365 + tid] = comp_b[tid];
    }
    __syncthreads();

    const int n = blockIdx.x * 256 + tid;
    if (n < 5632) Mnext[n] = 0.f;   // zero other M buffer for next iteration

    float spv[NCH], blv[NCH];
    #pragma unroll
    for (int c = 0; c < NCH; c++) { spv[c] = spo[(size_t)c * NPIX + n]; blv[c] = 0.f; }
    for (int mc = 0; mc < nmc; mc++)
        #pragma unroll
        for (int c = 0; c < NCH; c++)
            blv[c] += blp[((size_t)mc * NCH + c) * NPIX + n];

    const float invS = 1.f / spv[21];
    const float invB = 1.f / blv[21];
    #pragma unroll
    for (int c = 0; c < NC; c++) { spv[c] *= invS; blv[c] *= invB; }

    float mp[NC];
    for (int o = 0; o < NC; o++) {
        float m = wsh[1323 + o] + wsh[1344 + o];
        #pragma unroll
        for (int c = 0; c < NC; c++)
            m += wsh[o * NC + c] * spv[c] + wsh[441 + o * NC + c] * blv[c];
        mp[o] = m;
    }
    float q[NC];
    for (int o = 0; o < NC; o++) {
        float m = wsh[1365 + o];
        #pragma unroll
        for (int c = 0; c < NC; c++) m += wsh[882 + o * NC + c] * mp[c];
        q[o] = u[(size_t)o * NPIX + n] - m;
    }

    float mx = q[0];
    #pragma unroll
    for (int o = 1; o < NC; o++) mx = fmaxf(mx, q[o]);
    float sum = 0.f;
    #pragma unroll
    for (int o = 0; o < NC; o++) { q[o] = __expf(q[o] - mx); sum += q[o]; }
    const float inv = 1.f / sum;
    #pragma unroll
    for (int o = 0; o < NC; o++) {
        const float sv = q[o] * inv;
        s[(size_t)o * NPIX + n] = sv;
        if (write_out) out[(size_t)o * NPIX + n] = sv;
    }
    s[(size_t)21 * NPIX + n] = 1.f;
}

extern "C" void kernel_launch(void* const* d_in, const int* in_sizes, int n_in,
                              void* d_out, int out_size, void* d_ws, size_t ws_size,
                              hipStream_t stream) {
    const float* img    = (const float*)d_in[0];
    const float* net_w  = (const float*)d_in[1];
    const float* net_b  = (const float*)d_in[2];
    const float* sp_w   = (const float*)d_in[3];
    const float* sp_b   = (const float*)d_in[4];
    const float* bl_w   = (const float*)d_in[5];
    const float* bl_b   = (const float*)d_in[6];
    const float* comp_w = (const float*)d_in[7];
    const float* comp_b = (const float*)d_in[8];

    float* u   = (float*)d_ws;                  // [22][NPIX] (21 used)
    float* s   = u + (size_t)NCH * NPIX;        // [22][NPIX]
    float* f   = s + (size_t)NCH * NPIX;        // [6][NPIX]
    float* sx  = f + (size_t)6 * NPIX;          // [22][NPIX]
    float* spo = sx + (size_t)NCH * NPIX;       // [22][NPIX]
    float* phi = spo + (size_t)NCH * NPIX;      // [252][NPIX]
    float* M   = phi + (size_t)NMON * NPIX;     // [2][5632] double-buffered
    float* gam = M + 2 * 5632;                  // [252] pad 256
    float* blp = gam + 256;                     // [nmc][22][NPIX]

    const size_t fixed = (size_t)(blp - (float*)d_ws);
    static const int chain[4] = {6, 3, 2, 1};
    int nmc = 1;
    for (int ci = 0; ci < 4; ci++) {
        if ((fixed + (size_t)chain[ci] * NCH * NPIX) * sizeof(float) <= ws_size) {
            nmc = chain[ci]; break;
        }
    }
    const int msz = NMON / nmc;

    float* out = (float*)d_out;

    prep_kernel<<<dim3(36), dim3(256), 0, stream>>>(img, net_w, net_b, u, s, f, M);
    phik_kernel<<<dim3(252, 4), dim3(256), 0, stream>>>(f, phi, gam);
    for (int it = 0; it < NITER; it++) {
        float* Mc = M + (it & 1) * 5632;
        float* Mn = M + ((it + 1) & 1) * 5632;
        kA_kernel<<<dim3(NMG * 36 + 132), dim3(256), 0, stream>>>(s, phi, sx, Mc);
        kB1_kernel<<<dim3(nmc * 36 + NCH * 36), dim3(256), 0, stream>>>(
            sx, phi, Mc, gam, spo, blp, nmc, msz);
        kB2_kernel<<<dim3(36), dim3(256), 0, stream>>>(
            spo, blp, nmc, u, Mn, sp_w, sp_b, bl_w, bl_b, comp_w, comp_b,
            s, out, it == NITER - 1 ? 1 : 0);
    }
}

// Round 7
// 279.114 us; speedup vs baseline: 3.9240x; 1.1372x over previous
//
#include <hip/hip_runtime.h>

#define NPIX 9216
#define IMH 96
#define IMW 96
#define NC 21
#define NCH 22          // 21 classes + norm channel
#define CP 24           // pixel-major channel pad
#define NMON 252        // monomials of degree <=5 in 5 vars
#define RAD 15
#define NITER 5
#define MG 11           // monomials per stage1 block
#define NMG 23          // ceil(252/11)
#define NMC 6           // stage2 monomial chunks
#define MSZ 42          // NMON/NMC
#define LDS_STRIDE 260  // float4-aligned, 65 words -> bank-spread rows

// spatial taps exp(-d^2/18), sigma=3
__constant__ float GW[16] = {
    1.0f, 0.945959f, 0.800737f, 0.606531f, 0.411112f, 0.249352f,
    0.135335f, 0.0657285f, 0.0285655f, 0.0111090f, 0.00386592f,
    0.00120386f, 0.000335463f, 8.36523e-05f, 1.86640e-05f, 3.72665e-06f};

// Taylor coeffs of exp(t) = sum a_k t^k (deg 5, tuned at c=0.52)
__constant__ float d_ak[6] = {0.59449500f, 0.59481184f, 0.29588267f,
                              0.10253333f, 0.02f, 0.00833333f};

// ---- prep1: unary conv per (class, px-chunk) + features + zero M0 ----
__global__ __launch_bounds__(64) void prep1_kernel(
    const float* __restrict__ img, const float* __restrict__ net_w,
    const float* __restrict__ net_b,
    float* __restrict__ u_pm, float* __restrict__ f_pm, float* __restrict__ M)
{
    __shared__ float wsh[28];
    const int bid = blockIdx.x, tid = threadIdx.x;
    if (bid < 21 * 144) {
        const int c = bid / 144, chunk = bid % 144;
        if (tid < 27) wsh[tid] = net_w[c * 27 + tid];
        if (tid == 28 % 64) wsh[27] = net_b[c];
        __syncthreads();
        const int px = chunk * 64 + tid;
        const int i = px / IMW, j = px % IMW;
        float acc = wsh[27];
        for (int ci = 0; ci < 3; ci++)
            for (int ky = 0; ky < 3; ky++)
                for (int kx = 0; kx < 3; kx++) {
                    const int ii = i + ky - 1, jj = j + kx - 1;
                    float v = 0.f;
                    if (ii >= 0 && ii < IMH && jj >= 0 && jj < IMW)
                        v = img[(ci * IMH + ii) * IMW + jj];
                    acc = fmaf(v, wsh[(ci * 3 + ky) * 3 + kx], acc);
                }
        u_pm[px * CP + c] = acc;
    } else {
        const int chunk = bid - 21 * 144;
        const int px = chunk * 64 + tid;
        if (px < 5632) M[px] = 0.f;
        const int i = px / IMW, j = px % IMW;
        const float f1 = (float)j * (1.0f / 160.0f);
        const float f2 = (float)i * (1.0f / 160.0f);
        const float f3 = img[0 * NPIX + px] * (1.0f / 3.0f);
        const float f4 = img[1 * NPIX + px] * (1.0f / 3.0f);
        const float f5 = img[2 * NPIX + px] * (1.0f / 3.0f);
        const float env = __expf(-0.5f * (f1*f1 + f2*f2 + f3*f3 + f4*f4 + f5*f5));
        float4* fp = (float4*)(f_pm + px * 8);
        fp[0] = make_float4(f1, f2, f3, f4);
        fp[1] = make_float4(f5, env, 0.f, 0.f);
    }
}

// ---- prep2: softmax -> s in both layouts ----
__global__ __launch_bounds__(64) void prep2_kernel(
    const float* __restrict__ u_pm, float* __restrict__ s_pm,
    float* __restrict__ s_cm)
{
    const int px = blockIdx.x * 64 + threadIdx.x;
    float a[NC];
    const float4* up = (const float4*)(u_pm + px * CP);
    #pragma unroll
    for (int v = 0; v < 5; v++) {
        const float4 t = up[v];
        a[4*v] = t.x; a[4*v+1] = t.y; a[4*v+2] = t.z; a[4*v+3] = t.w;
    }
    a[20] = u_pm[px * CP + 20];
    float mx = a[0];
    #pragma unroll
    for (int o = 1; o < NC; o++) mx = fmaxf(mx, a[o]);
    float sum = 0.f;
    #pragma unroll
    for (int o = 0; o < NC; o++) { a[o] = __expf(a[o] - mx); sum += a[o]; }
    const float inv = 1.f / sum;
    #pragma unroll
    for (int o = 0; o < NC; o++) a[o] *= inv;
    float4* sp = (float4*)(s_pm + px * CP);
    sp[0] = make_float4(a[0], a[1], a[2], a[3]);
    sp[1] = make_float4(a[4], a[5], a[6], a[7]);
    sp[2] = make_float4(a[8], a[9], a[10], a[11]);
    sp[3] = make_float4(a[12], a[13], a[14], a[15]);
    sp[4] = make_float4(a[16], a[17], a[18], a[19]);
    sp[5] = make_float4(a[20], 1.f, 0.f, 0.f);
    #pragma unroll
    for (int o = 0; o < NC; o++) s_cm[(size_t)o * NPIX + px] = a[o];
    s_cm[(size_t)21 * NPIX + px] = 1.f;
}

// ---- phik: phi[m][px] = sqrt(gamma_m) * env * f^m ----
__global__ __launch_bounds__(256) void phik_kernel(
    const float* __restrict__ f_pm, float* __restrict__ phi)
{
    const int m = blockIdx.x, tid = threadIdx.x;
    int e1 = 0, e2 = 0, e3 = 0, e4 = 0, e5 = 0, cnt = 0;
    bool done = false;
    for (int a = 0; a <= 5 && !done; a++)
        for (int b2 = 0; b2 <= 5 - a && !done; b2++)
            for (int c = 0; c <= 5 - a - b2 && !done; c++)
                for (int d = 0; d <= 5 - a - b2 - c && !done; d++) {
                    const int rem = 5 - a - b2 - c - d;
                    if (m - cnt <= rem) {
                        e1 = a; e2 = b2; e3 = c; e4 = d; e5 = m - cnt; done = true;
                    } else cnt += rem + 1;
                }
    const float fact[6] = {1.f, 1.f, 2.f, 6.f, 24.f, 120.f};
    const int k = e1 + e2 + e3 + e4 + e5;
    const float sg = sqrtf(d_ak[k] * fact[k] /
                           (fact[e1] * fact[e2] * fact[e3] * fact[e4] * fact[e5]));
    for (int kk = 0; kk < 9; kk++) {
        const int px = blockIdx.y * 2304 + kk * 256 + tid;
        const float4 fa = *(const float4*)(f_pm + px * 8);
        const float4 fb = *(const float4*)(f_pm + px * 8 + 4);
        float p = fb.y * sg;   // env * sqrt(gamma)
        for (int q = 0; q < e1; q++) p *= fa.x;
        for (int q = 0; q < e2; q++) p *= fa.y;
        for (int q = 0; q < e3; q++) p *= fa.z;
        for (int q = 0; q < e4; q++) p *= fa.w;
        for (int q = 0; q < e5; q++) p *= fb.x;
        phi[(size_t)m * NPIX + px] = p;
    }
}

// ---- kA: stage1 GEMM (LDS b128 dot, atomic M) || conv-x ----
__global__ __launch_bounds__(256) void kA_kernel(
    const float* __restrict__ s_pm, const float* __restrict__ s_cm,
    const float* __restrict__ phi, float* __restrict__ sx, float* __restrict__ M)
{
    __shared__ float smem[NCH * LDS_STRIDE + MG * LDS_STRIDE];
    const int bid = blockIdx.x, tid = threadIdx.x;
    if (bid < NMG * 36) {
        const int g = bid / 36, chunk = bid % 36;
        const int m0 = g * MG;
        const int mcnt = (NMON - m0 < MG) ? (NMON - m0) : MG;
        float* s_sh = smem;
        float* p_sh = smem + NCH * LDS_STRIDE;
        {   // s tile: thread = px, 6 float4 loads, 22 scalar LDS writes
            const float4* sp = (const float4*)(s_pm + (size_t)(chunk * 256 + tid) * CP);
            #pragma unroll
            for (int v = 0; v < 6; v++) {
                const float4 t = sp[v];
                const int c = 4 * v;
                if (c < NCH)     s_sh[c * LDS_STRIDE + tid] = t.x;
                if (c + 1 < NCH) s_sh[(c + 1) * LDS_STRIDE + tid] = t.y;
                if (c + 2 < NCH) s_sh[(c + 2) * LDS_STRIDE + tid] = t.z;
                if (c + 3 < NCH) s_sh[(c + 3) * LDS_STRIDE + tid] = t.w;
            }
        }
        for (int idx = tid; idx < mcnt * 64; idx += 256) {
            const int mm = idx >> 6, p4 = idx & 63;
            const float4 t = *(const float4*)(phi + (size_t)(m0 + mm) * NPIX +
                                              chunk * 256 + p4 * 4);
            *(float4*)(p_sh + mm * LDS_STRIDE + p4 * 4) = t;
        }
        __syncthreads();
        const int c = tid % NCH, msub = tid / NCH;
        if (msub < mcnt) {
            const float* sr = s_sh + c * LDS_STRIDE;
            const float* pr = p_sh + msub * LDS_STRIDE;
            float acc = 0.f;
            for (int p4 = 0; p4 < 64; p4++) {
                const float4 sv = *(const float4*)(sr + p4 * 4);
                const float4 pv = *(const float4*)(pr + p4 * 4);
                acc += pv.x * sv.x + pv.y * sv.y + pv.z * sv.z + pv.w * sv.w;
            }
            atomicAdd(&M[(m0 + msub) * NCH + c], acc);
        }
    } else {
        for (int u2 = bid - NMG * 36; u2 < NCH * 36; u2 += 132) {
            const int ch = u2 / 36, pc = u2 % 36;
            const int n = pc * 256 + tid, j = n % IMW;
            const float* row = s_cm + (size_t)ch * NPIX + (n - j);
            float a = GW[0] * row[j];
            #pragma unroll
            for (int d = 1; d <= RAD; d++) {
                const float l = (j - d >= 0) ? row[j - d] : 0.f;
                const float r = (j + d < IMW) ? row[j + d] : 0.f;
                a = fmaf(GW[d], l + r, a);
            }
            sx[(size_t)ch * NPIX + n] = a;
        }
    }
}

// ---- kB1: stage2 partials -> blp_pm  ||  conv-y -> spo_pm ----
__global__ __launch_bounds__(256) void kB1_kernel(
    const float* __restrict__ sx, const float* __restrict__ phi,
    const float* __restrict__ M,
    float* __restrict__ spo_pm, float* __restrict__ blp_pm)
{
    const int bid = blockIdx.x, tid = threadIdx.x;
    if (bid < NMC * 36) {
        __shared__ float Msh[MSZ * NCH];
        const int mc = bid / 36, pc = bid % 36;
        const int m0 = mc * MSZ;
        for (int i2 = tid; i2 < MSZ * NCH; i2 += 256) Msh[i2] = M[m0 * NCH + i2];
        __syncthreads();
        const int px = pc * 256 + tid;
        float acc[NCH];
        #pragma unroll
        for (int c = 0; c < NCH; c++) acc[c] = 0.f;
        for (int mm = 0; mm < MSZ; mm++) {
            const float p = phi[(size_t)(m0 + mm) * NPIX + px];
            const float* Mr = Msh + mm * NCH;
            #pragma unroll
            for (int c = 0; c < NCH; c++) acc[c] = fmaf(p, Mr[c], acc[c]);
        }
        float4* bp = (float4*)(blp_pm + ((size_t)mc * NPIX + px) * CP);
        bp[0] = make_float4(acc[0], acc[1], acc[2], acc[3]);
        bp[1] = make_float4(acc[4], acc[5], acc[6], acc[7]);
        bp[2] = make_float4(acc[8], acc[9], acc[10], acc[11]);
        bp[3] = make_float4(acc[12], acc[13], acc[14], acc[15]);
        bp[4] = make_float4(acc[16], acc[17], acc[18], acc[19]);
        bp[5] = make_float4(acc[20], acc[21], 0.f, 0.f);
    } else {
        const int u2 = bid - NMC * 36;
        const int ch = u2 / 36, pc = u2 % 36;
        const int n = pc * 256 + tid, i = n / IMW;
        const float* plane = sx + (size_t)ch * NPIX;
        float a = GW[0] * plane[n];
        #pragma unroll
        for (int d = 1; d <= RAD; d++) {
            const float t = (i - d >= 0) ? plane[n - d * IMW] : 0.f;
            const float b = (i + d < IMH) ? plane[n + d * IMW] : 0.f;
            a = fmaf(GW[d], t + b, a);
        }
        spo_pm[(size_t)n * CP + ch] = a;
    }
}

// ---- kB2: combine = normalize + compat + softmax + write s (both layouts) ----
__global__ __launch_bounds__(64) void kB2_kernel(
    const float* __restrict__ spo_pm, const float* __restrict__ blp_pm,
    const float* __restrict__ u_pm, float* __restrict__ Mnext,
    const float* __restrict__ sp_w, const float* __restrict__ sp_b,
    const float* __restrict__ bl_w, const float* __restrict__ bl_b,
    const float* __restrict__ comp_w, const float* __restrict__ comp_b,
    float* __restrict__ s_pm, float* __restrict__ s_cm,
    float* __restrict__ out, int write_out)
{
    __shared__ float wsh[1386 + 63];
    const int tid = threadIdx.x;
    for (int i = tid; i < 441; i += 64) {
        wsh[i] = sp_w[i]; wsh[441 + i] = bl_w[i]; wsh[882 + i] = comp_w[i];
    }
    if (tid < 21) {
        wsh[1323 + tid] = sp_b[tid]; wsh[1344 + tid] = bl_b[tid];
        wsh[1365 + tid] = comp_b[tid];
    }
    __syncthreads();

    const int n = blockIdx.x * 64 + tid;
    if (n < 5632) Mnext[n] = 0.f;

    float spv[NCH], blv[NCH];
    {
        const float4* sp = (const float4*)(spo_pm + (size_t)n * CP);
        #pragma unroll
        for (int v = 0; v < 5; v++) {
            const float4 t = sp[v];
            spv[4*v] = t.x; spv[4*v+1] = t.y; spv[4*v+2] = t.z; spv[4*v+3] = t.w;
        }
        const float4 t = sp[5];
        spv[20] = t.x; spv[21] = t.y;
    }
    #pragma unroll
    for (int c = 0; c < NCH; c++) blv[c] = 0.f;
    for (int mc = 0; mc < NMC; mc++) {
        const float4* bp = (const float4*)(blp_pm + ((size_t)mc * NPIX + n) * CP);
        #pragma unroll
        for (int v = 0; v < 5; v++) {
            const float4 t = bp[v];
            blv[4*v] += t.x; blv[4*v+1] += t.y; blv[4*v+2] += t.z; blv[4*v+3] += t.w;
        }
        const float4 t = bp[5];
        blv[20] += t.x; blv[21] += t.y;
    }

    const float invS = 1.f / spv[21];
    const float invB = 1.f / blv[21];
    #pragma unroll
    for (int c = 0; c < NC; c++) { spv[c] *= invS; blv[c] *= invB; }

    float mp[NC];
    for (int o = 0; o < NC; o++) {
        float m = wsh[1323 + o] + wsh[1344 + o];
        #pragma unroll
        for (int c = 0; c < NC; c++)
            m += wsh[o * NC + c] * spv[c] + wsh[441 + o * NC + c] * blv[c];
        mp[o] = m;
    }
    float q[NC];
    for (int o = 0; o < NC; o++) {
        float m = wsh[1365 + o];
        #pragma unroll
        for (int c = 0; c < NC; c++) m += wsh[882 + o * NC + c] * mp[c];
        q[o] = u_pm[(size_t)n * CP + o] - m;
    }

    float mx = q[0];
    #pragma unroll
    for (int o = 1; o < NC; o++) mx = fmaxf(mx, q[o]);
    float sum = 0.f;
    #pragma unroll
    for (int o = 0; o < NC; o++) { q[o] = __expf(q[o] - mx); sum += q[o]; }
    const float inv = 1.f / sum;
    #pragma unroll
    for (int o = 0; o < NC; o++) q[o] *= inv;

    float4* sp = (float4*)(s_pm + (size_t)n * CP);
    sp[0] = make_float4(q[0], q[1], q[2], q[3]);
    sp[1] = make_float4(q[4], q[5], q[6], q[7]);
    sp[2] = make_float4(q[8], q[9], q[10], q[11]);
    sp[3] = make_float4(q[12], q[13], q[14], q[15]);
    sp[4] = make_float4(q[16], q[17], q[18], q[19]);
    sp[5] = make_float4(q[20], 1.f, 0.f, 0.f);
    #pragma unroll
    for (int o = 0; o < NC; o++) s_cm[(size_t)o * NPIX + n] = q[o];
    s_cm[(size_t)21 * NPIX + n] = 1.f;
    if (write_out)
        #pragma unroll
        for (int o = 0; o < NC; o++) out[(size_t)o * NPIX + n] = q[o];
}

extern "C" void kernel_launch(void* const* d_in, const int* in_sizes, int n_in,
                              void* d_out, int out_size, void* d_ws, size_t ws_size,
                              hipStream_t stream) {
    const float* img    = (const float*)d_in[0];
    const float* net_w  = (const float*)d_in[1];
    const float* net_b  = (const float*)d_in[2];
    const float* sp_w   = (const float*)d_in[3];
    const float* sp_b   = (const float*)d_in[4];
    const float* bl_w   = (const float*)d_in[5];
    const float* bl_b   = (const float*)d_in[6];
    const float* comp_w = (const float*)d_in[7];
    const float* comp_b = (const float*)d_in[8];

    float* u_pm   = (float*)d_ws;                    // [NPIX][24]
    float* s_pm   = u_pm + (size_t)NPIX * CP;        // [NPIX][24]
    float* s_cm   = s_pm + (size_t)NPIX * CP;        // [22][NPIX]
    float* f_pm   = s_cm + (size_t)NCH * NPIX;       // [NPIX][8]
    float* sx     = f_pm + (size_t)NPIX * 8;         // [22][NPIX]
    float* spo_pm = sx + (size_t)NCH * NPIX;         // [NPIX][24]
    float* phi    = spo_pm + (size_t)NPIX * CP;      // [252][NPIX]
    float* M      = phi + (size_t)NMON * NPIX;       // [2][5632]
    float* blp_pm = M + 2 * 5632;                    // [6][NPIX][24]

    float* out = (float*)d_out;

    prep1_kernel<<<dim3(21 * 144 + 144), dim3(64), 0, stream>>>(
        img, net_w, net_b, u_pm, f_pm, M);
    prep2_kernel<<<dim3(144), dim3(64), 0, stream>>>(u_pm, s_pm, s_cm);
    phik_kernel<<<dim3(252, 4), dim3(256), 0, stream>>>(f_pm, phi);
    for (int it = 0; it < NITER; it++) {
        float* Mc = M + (it & 1) * 5632;
        float* Mn = M + ((it + 1) & 1) * 5632;
        kA_kernel<<<dim3(NMG * 36 + 132), dim3(256), 0, stream>>>(
            s_pm, s_cm, phi, sx, Mc);
        kB1_kernel<<<dim3(NMC * 36 + NCH * 36), dim3(256), 0, stream>>>(
            sx, phi, Mc, spo_pm, blp_pm);
        kB2_kernel<<<dim3(144), dim3(64), 0, stream>>>(
            spo_pm, blp_pm, u_pm, Mn, sp_w, sp_b, bl_w, bl_b, comp_w, comp_b,
            s_pm, s_cm, out, it == NITER - 1 ? 1 : 0);
    }
}

// Round 8
// 243.453 us; speedup vs baseline: 4.4988x; 1.1465x over previous
//
#include <hip/hip_runtime.h>

#define NPIX 9216
#define IMH 96
#define IMW 96
#define NC 21
#define NCH 22          // 21 classes + norm channel
#define CP 24           // pixel-major channel pad
#define NMON 126        // monomials of degree <=4 in 5 vars
#define RAD 15
#define NITER 5
#define MG 11           // monomials per stage1 block
#define NMG 12          // ceil(126/11)
#define LDSS 260        // stage1 LDS pitch (float4-aligned, bank-spread)
#define MPAD 2816       // M buffer stride (>=126*22)

// spatial taps exp(-d^2/18), sigma=3
__constant__ float GW[16] = {
    1.0f, 0.945959f, 0.800737f, 0.606531f, 0.411112f, 0.249352f,
    0.135335f, 0.0657285f, 0.0285655f, 0.0111090f, 0.00386592f,
    0.00120386f, 0.000335463f, 8.36523e-05f, 1.86640e-05f, 3.72665e-06f};

// near-minimax deg-4 poly for exp(t) on [0, 1.0384] (Chebyshev-derived, all >0)
__constant__ float d_bk[5] = {1.000000f, 0.998959f, 0.509936f, 0.139441f, 0.070024f};

// ---- P1: unary conv per (class, px-chunk) + features + zero M0 ----
__global__ __launch_bounds__(64) void p1_kernel(
    const float* __restrict__ img, const float* __restrict__ net_w,
    const float* __restrict__ net_b,
    float* __restrict__ u_pm, float* __restrict__ f_pm, float* __restrict__ M0)
{
    __shared__ float wsh[28];
    const int bid = blockIdx.x, tid = threadIdx.x;
    if (bid < 21 * 144) {
        const int c = bid / 144, chunk = bid % 144;
        if (tid < 27) wsh[tid] = net_w[c * 27 + tid];
        if (tid == 28) wsh[27] = net_b[c];
        __syncthreads();
        const int px = chunk * 64 + tid;
        const int i = px / IMW, j = px % IMW;
        float acc = wsh[27];
        for (int ci = 0; ci < 3; ci++)
            for (int ky = 0; ky < 3; ky++)
                for (int kx = 0; kx < 3; kx++) {
                    const int ii = i + ky - 1, jj = j + kx - 1;
                    float v = 0.f;
                    if (ii >= 0 && ii < IMH && jj >= 0 && jj < IMW)
                        v = img[(ci * IMH + ii) * IMW + jj];
                    acc = fmaf(v, wsh[(ci * 3 + ky) * 3 + kx], acc);
                }
        u_pm[px * CP + c] = acc;
    } else {
        const int chunk = bid - 21 * 144;
        const int px = chunk * 64 + tid;
        if (px < 2772) M0[px] = 0.f;
        const int i = px / IMW, j = px % IMW;
        const float f1 = (float)j * (1.0f / 160.0f);
        const float f2 = (float)i * (1.0f / 160.0f);
        const float f3 = img[0 * NPIX + px] * (1.0f / 3.0f);
        const float f4 = img[1 * NPIX + px] * (1.0f / 3.0f);
        const float f5 = img[2 * NPIX + px] * (1.0f / 3.0f);
        const float env = __expf(-0.5f * (f1*f1 + f2*f2 + f3*f3 + f4*f4 + f5*f5));
        float4* fp = (float4*)(f_pm + px * 8);
        fp[0] = make_float4(f1, f2, f3, f4);
        fp[1] = make_float4(f5, env, 0.f, 0.f);
    }
}

// ---- P2: softmax -> s (both layouts)  ||  phi rows (sqrt(gamma) folded) ----
__global__ __launch_bounds__(64) void p2_kernel(
    const float* __restrict__ u_pm, const float* __restrict__ f_pm,
    float* __restrict__ s_pm, float* __restrict__ s_cm, float* __restrict__ phi)
{
    const int bid = blockIdx.x, tid = threadIdx.x;
    if (bid < 144) {
        const int px = bid * 64 + tid;
        float a[NC];
        const float4* up = (const float4*)(u_pm + px * CP);
        #pragma unroll
        for (int v = 0; v < 5; v++) {
            const float4 t = up[v];
            a[4*v] = t.x; a[4*v+1] = t.y; a[4*v+2] = t.z; a[4*v+3] = t.w;
        }
        a[20] = u_pm[px * CP + 20];
        float mx = a[0];
        #pragma unroll
        for (int o = 1; o < NC; o++) mx = fmaxf(mx, a[o]);
        float sum = 0.f;
        #pragma unroll
        for (int o = 0; o < NC; o++) { a[o] = __expf(a[o] - mx); sum += a[o]; }
        const float inv = 1.f / sum;
        #pragma unroll
        for (int o = 0; o < NC; o++) a[o] *= inv;
        float4* sp = (float4*)(s_pm + px * CP);
        sp[0] = make_float4(a[0], a[1], a[2], a[3]);
        sp[1] = make_float4(a[4], a[5], a[6], a[7]);
        sp[2] = make_float4(a[8], a[9], a[10], a[11]);
        sp[3] = make_float4(a[12], a[13], a[14], a[15]);
        sp[4] = make_float4(a[16], a[17], a[18], a[19]);
        sp[5] = make_float4(a[20], 1.f, 0.f, 0.f);
        #pragma unroll
        for (int o = 0; o < NC; o++) s_cm[(size_t)o * NPIX + px] = a[o];
        s_cm[(size_t)21 * NPIX + px] = 1.f;
    } else {
        const int t2 = bid - 144;
        const int m = t2 >> 2, quad = t2 & 3;
        int e1 = 0, e2 = 0, e3 = 0, e4 = 0, e5 = 0, cnt = 0;
        bool done = false;
        for (int a = 0; a <= 4 && !done; a++)
            for (int b2 = 0; b2 <= 4 - a && !done; b2++)
                for (int c = 0; c <= 4 - a - b2 && !done; c++)
                    for (int d = 0; d <= 4 - a - b2 - c && !done; d++) {
                        const int rem = 4 - a - b2 - c - d;
                        if (m - cnt <= rem) {
                            e1 = a; e2 = b2; e3 = c; e4 = d; e5 = m - cnt; done = true;
                        } else cnt += rem + 1;
                    }
        const float fact[5] = {1.f, 1.f, 2.f, 6.f, 24.f};
        const int k = e1 + e2 + e3 + e4 + e5;
        const float sg = sqrtf(d_bk[k] * fact[k] /
                               (fact[e1] * fact[e2] * fact[e3] * fact[e4] * fact[e5]));
        for (int kk = 0; kk < 36; kk++) {
            const int px = quad * 2304 + kk * 64 + tid;
            const float4 fa = *(const float4*)(f_pm + px * 8);
            const float4 fb = *(const float4*)(f_pm + px * 8 + 4);
            float p = fb.y * sg;   // env * sqrt(gamma)
            for (int q = 0; q < e1; q++) p *= fa.x;
            for (int q = 0; q < e2; q++) p *= fa.y;
            for (int q = 0; q < e3; q++) p *= fa.z;
            for (int q = 0; q < e4; q++) p *= fa.w;
            for (int q = 0; q < e5; q++) p *= fb.x;
            phi[(size_t)m * NPIX + px] = p;
        }
    }
}

// ---- K1: stage1 GEMM (LDS b128 dot, atomic M) || conv-x ----
__global__ __launch_bounds__(256) void k1_kernel(
    const float* __restrict__ s_pm, const float* __restrict__ s_cm,
    const float* __restrict__ phi, float* __restrict__ sx, float* __restrict__ M)
{
    __shared__ float smem[(NCH + MG) * LDSS];
    const int bid = blockIdx.x, tid = threadIdx.x;
    if (bid < NMG * 36) {
        const int g = bid / 36, chunk = bid % 36;
        const int m0 = g * MG;
        const int mcnt = (NMON - m0 < MG) ? (NMON - m0) : MG;
        float* s_sh = smem;
        float* p_sh = smem + NCH * LDSS;
        {
            const float4* sp = (const float4*)(s_pm + (size_t)(chunk * 256 + tid) * CP);
            #pragma unroll
            for (int v = 0; v < 6; v++) {
                const float4 t = sp[v];
                const int c = 4 * v;
                if (c < NCH)     s_sh[c * LDSS + tid] = t.x;
                if (c + 1 < NCH) s_sh[(c + 1) * LDSS + tid] = t.y;
                if (c + 2 < NCH) s_sh[(c + 2) * LDSS + tid] = t.z;
                if (c + 3 < NCH) s_sh[(c + 3) * LDSS + tid] = t.w;
            }
        }
        for (int idx = tid; idx < mcnt * 64; idx += 256) {
            const int mm = idx >> 6, p4 = idx & 63;
            const float4 t = *(const float4*)(phi + (size_t)(m0 + mm) * NPIX +
                                              chunk * 256 + p4 * 4);
            *(float4*)(p_sh + mm * LDSS + p4 * 4) = t;
        }
        __syncthreads();
        const int c = tid % NCH, msub = tid / NCH;
        if (msub < mcnt) {
            const float* sr = s_sh + c * LDSS;
            const float* pr = p_sh + msub * LDSS;
            float acc = 0.f;
            for (int p4 = 0; p4 < 64; p4++) {
                const float4 sv = *(const float4*)(sr + p4 * 4);
                const float4 pv = *(const float4*)(pr + p4 * 4);
                acc += pv.x * sv.x + pv.y * sv.y + pv.z * sv.z + pv.w * sv.w;
            }
            atomicAdd(&M[(m0 + msub) * NCH + c], acc);
        }
    } else {
        const int u2 = bid - NMG * 36;        // [0, 792)
        const int ch = u2 / 36, pc = u2 % 36;
        const int n = pc * 256 + tid, j = n % IMW;
        const float* row = s_cm + (size_t)ch * NPIX + (n - j);
        float a = GW[0] * row[j];
        #pragma unroll
        for (int d = 1; d <= RAD; d++) {
            const float l = (j - d >= 0) ? row[j - d] : 0.f;
            const float r = (j + d < IMW) ? row[j + d] : 0.f;
            a = fmaf(GW[d], l + r, a);
        }
        sx[(size_t)ch * NPIX + n] = a;
    }
}

// ---- K2: conv-y + stage2 + combine + softmax, one block per 64 px ----
__global__ __launch_bounds__(256) void k2_kernel(
    const float* __restrict__ sx, const float* __restrict__ phi,
    const float* __restrict__ M, float* __restrict__ Mnext,
    const float* __restrict__ u_pm,
    const float* __restrict__ sp_w, const float* __restrict__ sp_b,
    const float* __restrict__ bl_w, const float* __restrict__ bl_b,
    const float* __restrict__ comp_w, const float* __restrict__ comp_b,
    float* __restrict__ s_pm, float* __restrict__ s_cm,
    float* __restrict__ out, int write_out)
{
    __shared__ float phi_sh[NMON * 64];   // 8064
    __shared__ float Msh[NMON * CP];      // 3024 (pitch 24, cols 22..23 zero)
    __shared__ float cy_sh[64 * 25];
    __shared__ float blv_sh[64 * 25];
    __shared__ float wsh[1449];
    const int tid = threadIdx.x;
    const int px0 = blockIdx.x * 64;

    for (int i = tid; i < NMON * CP; i += 256) {
        const int mm = i / CP, c = i % CP;
        Msh[i] = (c < NCH) ? M[mm * NCH + c] : 0.f;
    }
    for (int i = tid; i < 441; i += 256) {
        wsh[i] = sp_w[i]; wsh[441 + i] = bl_w[i]; wsh[882 + i] = comp_w[i];
    }
    if (tid < 21) {
        wsh[1323 + tid] = sp_b[tid]; wsh[1344 + tid] = bl_b[tid];
        wsh[1365 + tid] = comp_b[tid];
    }
    if (blockIdx.x < 44) {
        const int i = blockIdx.x * 64 + tid;
        if (i < 2772) Mnext[i] = 0.f;
    }

    // phi tile [126][64], row-major (coalesced global, conflict-free LDS)
    for (int idx = tid; idx < NMON * 16; idx += 256) {
        const int m = idx >> 4, grp = idx & 15;
        *(float4*)(phi_sh + m * 64 + grp * 4) =
            *(const float4*)(phi + (size_t)m * NPIX + px0 + grp * 4);
    }
    // conv-y for 22 channels x 64 px
    for (int task = tid; task < NCH * 64; task += 256) {
        const int ch = task >> 6, p = task & 63;
        const int n = px0 + p, i = n / IMW;
        const float* plane = sx + (size_t)ch * NPIX;
        float a = GW[0] * plane[n];
        #pragma unroll
        for (int d = 1; d <= RAD; d++) {
            const float t = (i - d >= 0) ? plane[n - d * IMW] : 0.f;
            const float b = (i + d < IMH) ? plane[n + d * IMW] : 0.f;
            a = fmaf(GW[d], t + b, a);
        }
        cy_sh[p * 25 + ch] = a;
    }
    __syncthreads();

    // stage2: wave = 6-channel group, lane = pixel
    {
        const int cq = tid >> 6, p = tid & 63;
        const int c0 = cq * 6;
        float acc[6] = {0.f, 0.f, 0.f, 0.f, 0.f, 0.f};
        for (int mm = 0; mm < NMON; mm++) {
            const float ph = phi_sh[mm * 64 + p];
            const float* Mr = Msh + mm * CP + c0;
            #pragma unroll
            for (int k = 0; k < 6; k++) acc[k] = fmaf(ph, Mr[k], acc[k]);
        }
        #pragma unroll
        for (int k = 0; k < 6; k++)
            if (c0 + k < NCH) blv_sh[p * 25 + c0 + k] = acc[k];
    }
    __syncthreads();

    // combine per pixel
    if (tid < 64) {
        const int n = px0 + tid;
        float spv[NCH], blv[NCH];
        #pragma unroll
        for (int c = 0; c < NCH; c++) {
            spv[c] = cy_sh[tid * 25 + c];
            blv[c] = blv_sh[tid * 25 + c];
        }
        const float invS = 1.f / spv[21];
        const float invB = 1.f / blv[21];
        #pragma unroll
        for (int c = 0; c < NC; c++) { spv[c] *= invS; blv[c] *= invB; }

        float mp[NC];
        for (int o = 0; o < NC; o++) {
            float m = wsh[1323 + o] + wsh[1344 + o];
            #pragma unroll
            for (int c = 0; c < NC; c++)
                m += wsh[o * NC + c] * spv[c] + wsh[441 + o * NC + c] * blv[c];
            mp[o] = m;
        }
        float q[NC];
        for (int o = 0; o < NC; o++) {
            float m = wsh[1365 + o];
            #pragma unroll
            for (int c = 0; c < NC; c++) m += wsh[882 + o * NC + c] * mp[c];
            q[o] = u_pm[(size_t)n * CP + o] - m;
        }
        float mx = q[0];
        #pragma unroll
        for (int o = 1; o < NC; o++) mx = fmaxf(mx, q[o]);
        float sum = 0.f;
        #pragma unroll
        for (int o = 0; o < NC; o++) { q[o] = __expf(q[o] - mx); sum += q[o]; }
        const float inv = 1.f / sum;
        #pragma unroll
        for (int o = 0; o < NC; o++) q[o] *= inv;

        float4* sp = (float4*)(s_pm + (size_t)n * CP);
        sp[0] = make_float4(q[0], q[1], q[2], q[3]);
        sp[1] = make_float4(q[4], q[5], q[6], q[7]);
        sp[2] = make_float4(q[8], q[9], q[10], q[11]);
        sp[3] = make_float4(q[12], q[13], q[14], q[15]);
        sp[4] = make_float4(q[16], q[17], q[18], q[19]);
        sp[5] = make_float4(q[20], 1.f, 0.f, 0.f);
        #pragma unroll
        for (int o = 0; o < NC; o++) s_cm[(size_t)o * NPIX + n] = q[o];
        s_cm[(size_t)21 * NPIX + n] = 1.f;
        if (write_out)
            #pragma unroll
            for (int o = 0; o < NC; o++) out[(size_t)o * NPIX + n] = q[o];
    }
}

extern "C" void kernel_launch(void* const* d_in, const int* in_sizes, int n_in,
                              void* d_out, int out_size, void* d_ws, size_t ws_size,
                              hipStream_t stream) {
    const float* img    = (const float*)d_in[0];
    const float* net_w  = (const float*)d_in[1];
    const float* net_b  = (const float*)d_in[2];
    const float* sp_w   = (const float*)d_in[3];
    const float* sp_b   = (const float*)d_in[4];
    const float* bl_w   = (const float*)d_in[5];
    const float* bl_b   = (const float*)d_in[6];
    const float* comp_w = (const float*)d_in[7];
    const float* comp_b = (const float*)d_in[8];

    float* u_pm = (float*)d_ws;                  // [NPIX][24]
    float* s_pm = u_pm + (size_t)NPIX * CP;      // [NPIX][24]
    float* s_cm = s_pm + (size_t)NPIX * CP;      // [22][NPIX]
    float* f_pm = s_cm + (size_t)NCH * NPIX;     // [NPIX][8]
    float* sx   = f_pm + (size_t)NPIX * 8;       // [22][NPIX]
    float* phi  = sx + (size_t)NCH * NPIX;       // [126][NPIX]
    float* M    = phi + (size_t)NMON * NPIX;     // [2][MPAD]

    float* out = (float*)d_out;

    p1_kernel<<<dim3(21 * 144 + 144), dim3(64), 0, stream>>>(
        img, net_w, net_b, u_pm, f_pm, M);
    p2_kernel<<<dim3(144 + NMON * 4), dim3(64), 0, stream>>>(
        u_pm, f_pm, s_pm, s_cm, phi);
    for (int it = 0; it < NITER; it++) {
        float* Mc = M + (it & 1) * MPAD;
        float* Mn = M + ((it + 1) & 1) * MPAD;
        k1_kernel<<<dim3(NMG * 36 + NCH * 36), dim3(256), 0, stream>>>(
            s_pm, s_cm, phi, sx, Mc);
        k2_kernel<<<dim3(144), dim3(256), 0, stream>>>(
            sx, phi, Mc, Mn, u_pm, sp_w, sp_b, bl_w, bl_b, comp_w, comp_b,
            s_pm, s_cm, out, it == NITER - 1 ? 1 : 0);
    }
}

// Round 9
// 227.828 us; speedup vs baseline: 4.8074x; 1.0686x over previous
//
#include <hip/hip_runtime.h>

#define NPIX 9216
#define IMH 96
#define IMW 96
#define NC 21
#define NCH 22          // 21 classes + norm channel
#define CP 24           // pixel-major channel pad
#define NMON 126        // monomials of degree <=4 in 5 vars
#define RAD 15
#define NITER 5
#define MG 11           // monomials per stage1 block
#define NMG 12          // ceil(126/11)
#define LDSS 260        // stage1 LDS pitch (float4-aligned, bank-spread)
#define MPAD 2816       // M buffer stride (>=126*22)

// spatial taps exp(-d^2/18), sigma=3
__constant__ float GW[16] = {
    1.0f, 0.945959f, 0.800737f, 0.606531f, 0.411112f, 0.249352f,
    0.135335f, 0.0657285f, 0.0285655f, 0.0111090f, 0.00386592f,
    0.00120386f, 0.000335463f, 8.36523e-05f, 1.86640e-05f, 3.72665e-06f};

// near-minimax deg-4 poly for exp(t) on [0, 1.0384] (all coeffs > 0)
__constant__ float d_bk[5] = {1.000000f, 0.998959f, 0.509936f, 0.139441f, 0.070024f};

// ---- P: unary conv + softmax + features + phi + zero M0, one dispatch ----
__global__ __launch_bounds__(64) void prep_kernel(
    const float* __restrict__ img, const float* __restrict__ net_w,
    const float* __restrict__ net_b,
    float* __restrict__ u_pm, float* __restrict__ s_pm, float* __restrict__ s_cm,
    float* __restrict__ phi, float* __restrict__ M0)
{
    __shared__ float wsh[567], bsh[21];
    __shared__ float sg_sh[NMON];
    __shared__ float ex_sh[NMON * 5];
    __shared__ float pt[64 * 25];       // per-thread pow tables (stride 25: bank-safe)
    const int tid = threadIdx.x;
    for (int i = tid; i < 567; i += 64) wsh[i] = net_w[i];
    if (tid < 21) bsh[tid] = net_b[tid];
    // decode monomial exponents + sqrt(gamma), 2 monomials per thread
    for (int m = tid; m < NMON; m += 64) {
        int e1 = 0, e2 = 0, e3 = 0, e4 = 0, e5 = 0, cnt = 0;
        bool done = false;
        for (int a = 0; a <= 4 && !done; a++)
            for (int b2 = 0; b2 <= 4 - a && !done; b2++)
                for (int c = 0; c <= 4 - a - b2 && !done; c++)
                    for (int d = 0; d <= 4 - a - b2 - c && !done; d++) {
                        const int rem = 4 - a - b2 - c - d;
                        if (m - cnt <= rem) {
                            e1 = a; e2 = b2; e3 = c; e4 = d; e5 = m - cnt; done = true;
                        } else cnt += rem + 1;
                    }
        const float fact[5] = {1.f, 1.f, 2.f, 6.f, 24.f};
        const int k = e1 + e2 + e3 + e4 + e5;
        sg_sh[m] = sqrtf(d_bk[k] * fact[k] /
                         (fact[e1] * fact[e2] * fact[e3] * fact[e4] * fact[e5]));
        ex_sh[m * 5 + 0] = (float)e1; ex_sh[m * 5 + 1] = (float)e2;
        ex_sh[m * 5 + 2] = (float)e3; ex_sh[m * 5 + 3] = (float)e4;
        ex_sh[m * 5 + 4] = (float)e5;
    }
    __syncthreads();

    const int px = blockIdx.x * 64 + tid;
    const int i = px / IMW, j = px % IMW;
    if (px < 2772) M0[px] = 0.f;

    // unary conv, all 21 classes
    float acc[NC];
    #pragma unroll
    for (int o = 0; o < NC; o++) acc[o] = bsh[o];
    for (int ci = 0; ci < 3; ci++)
        for (int ky = 0; ky < 3; ky++)
            for (int kx = 0; kx < 3; kx++) {
                const int ii = i + ky - 1, jj = j + kx - 1;
                float v = 0.f;
                if (ii >= 0 && ii < IMH && jj >= 0 && jj < IMW)
                    v = img[(ci * IMH + ii) * IMW + jj];
                #pragma unroll
                for (int o = 0; o < NC; o++)
                    acc[o] = fmaf(v, wsh[(ci * 3 + ky) * 3 + kx + o * 27], acc[o]);
            }
    {   // u then softmax
        float4* up = (float4*)(u_pm + (size_t)px * CP);
        up[0] = make_float4(acc[0], acc[1], acc[2], acc[3]);
        up[1] = make_float4(acc[4], acc[5], acc[6], acc[7]);
        up[2] = make_float4(acc[8], acc[9], acc[10], acc[11]);
        up[3] = make_float4(acc[12], acc[13], acc[14], acc[15]);
        up[4] = make_float4(acc[16], acc[17], acc[18], acc[19]);
        up[5] = make_float4(acc[20], 0.f, 0.f, 0.f);
    }
    float mx = acc[0];
    #pragma unroll
    for (int o = 1; o < NC; o++) mx = fmaxf(mx, acc[o]);
    float sum = 0.f;
    #pragma unroll
    for (int o = 0; o < NC; o++) { acc[o] = __expf(acc[o] - mx); sum += acc[o]; }
    const float inv = 1.f / sum;
    #pragma unroll
    for (int o = 0; o < NC; o++) acc[o] *= inv;
    {
        float4* sp = (float4*)(s_pm + (size_t)px * CP);
        sp[0] = make_float4(acc[0], acc[1], acc[2], acc[3]);
        sp[1] = make_float4(acc[4], acc[5], acc[6], acc[7]);
        sp[2] = make_float4(acc[8], acc[9], acc[10], acc[11]);
        sp[3] = make_float4(acc[12], acc[13], acc[14], acc[15]);
        sp[4] = make_float4(acc[16], acc[17], acc[18], acc[19]);
        sp[5] = make_float4(acc[20], 1.f, 0.f, 0.f);
    }
    #pragma unroll
    for (int o = 0; o < NC; o++) s_cm[(size_t)o * NPIX + px] = acc[o];
    s_cm[(size_t)21 * NPIX + px] = 1.f;

    // features + pow tables + phi
    const float fv[5] = {(float)j * (1.0f / 160.0f), (float)i * (1.0f / 160.0f),
                         img[0 * NPIX + px] * (1.0f / 3.0f),
                         img[1 * NPIX + px] * (1.0f / 3.0f),
                         img[2 * NPIX + px] * (1.0f / 3.0f)};
    const float env = __expf(-0.5f * (fv[0]*fv[0] + fv[1]*fv[1] + fv[2]*fv[2] +
                                      fv[3]*fv[3] + fv[4]*fv[4]));
    #pragma unroll
    for (int v = 0; v < 5; v++) {
        float p = 1.f;
        #pragma unroll
        for (int e = 0; e < 5; e++) { pt[tid * 25 + v * 5 + e] = p; p *= fv[v]; }
    }
    for (int m = 0; m < NMON; m++) {
        float p = env * sg_sh[m];
        p *= pt[tid * 25 + 0 + (int)ex_sh[m * 5 + 0]];
        p *= pt[tid * 25 + 5 + (int)ex_sh[m * 5 + 1]];
        p *= pt[tid * 25 + 10 + (int)ex_sh[m * 5 + 2]];
        p *= pt[tid * 25 + 15 + (int)ex_sh[m * 5 + 3]];
        p *= pt[tid * 25 + 20 + (int)ex_sh[m * 5 + 4]];
        phi[(size_t)m * NPIX + px] = p;
    }
}

// ---- K1: stage1 GEMM (LDS b128 dot, atomic M) || conv-x ----
__global__ __launch_bounds__(256) void k1_kernel(
    const float* __restrict__ s_pm, const float* __restrict__ s_cm,
    const float* __restrict__ phi, float* __restrict__ sx, float* __restrict__ M)
{
    __shared__ float smem[(NCH + MG) * LDSS];
    const int bid = blockIdx.x, tid = threadIdx.x;
    if (bid < NMG * 36) {
        const int g = bid / 36, chunk = bid % 36;
        const int m0 = g * MG;
        const int mcnt = (NMON - m0 < MG) ? (NMON - m0) : MG;
        float* s_sh = smem;
        float* p_sh = smem + NCH * LDSS;
        {
            const float4* sp = (const float4*)(s_pm + (size_t)(chunk * 256 + tid) * CP);
            #pragma unroll
            for (int v = 0; v < 6; v++) {
                const float4 t = sp[v];
                const int c = 4 * v;
                if (c < NCH)     s_sh[c * LDSS + tid] = t.x;
                if (c + 1 < NCH) s_sh[(c + 1) * LDSS + tid] = t.y;
                if (c + 2 < NCH) s_sh[(c + 2) * LDSS + tid] = t.z;
                if (c + 3 < NCH) s_sh[(c + 3) * LDSS + tid] = t.w;
            }
        }
        for (int idx = tid; idx < mcnt * 64; idx += 256) {
            const int mm = idx >> 6, p4 = idx & 63;
            const float4 t = *(const float4*)(phi + (size_t)(m0 + mm) * NPIX +
                                              chunk * 256 + p4 * 4);
            *(float4*)(p_sh + mm * LDSS + p4 * 4) = t;
        }
        __syncthreads();
        const int c = tid % NCH, msub = tid / NCH;
        if (msub < mcnt) {
            const float* sr = s_sh + c * LDSS;
            const float* pr = p_sh + msub * LDSS;
            float acc = 0.f;
            for (int p4 = 0; p4 < 64; p4++) {
                const float4 sv = *(const float4*)(sr + p4 * 4);
                const float4 pv = *(const float4*)(pr + p4 * 4);
                acc += pv.x * sv.x + pv.y * sv.y + pv.z * sv.z + pv.w * sv.w;
            }
            atomicAdd(&M[(m0 + msub) * NCH + c], acc);
        }
    } else {
        const int u2 = bid - NMG * 36;        // [0, 792)
        const int ch = u2 / 36, pc = u2 % 36;
        const int n = pc * 256 + tid, j = n % IMW;
        const float* row = s_cm + (size_t)ch * NPIX + (n - j);
        float a = GW[0] * row[j];
        #pragma unroll
        for (int d = 1; d <= RAD; d++) {
            const float l = (j - d >= 0) ? row[j - d] : 0.f;
            const float r = (j + d < IMW) ? row[j + d] : 0.f;
            a = fmaf(GW[d], l + r, a);
        }
        sx[(size_t)ch * NPIX + n] = a;
    }
}

// ---- K2: conv-y + stage2 + combine + softmax, 32 px per block ----
__global__ __launch_bounds__(256) void k2_kernel(
    const float* __restrict__ sx, const float* __restrict__ phi,
    const float* __restrict__ M, float* __restrict__ Mnext,
    const float* __restrict__ u_pm,
    const float* __restrict__ sp_w, const float* __restrict__ sp_b,
    const float* __restrict__ bl_w, const float* __restrict__ bl_b,
    const float* __restrict__ comp_w, const float* __restrict__ comp_b,
    float* __restrict__ s_pm, float* __restrict__ s_cm,
    float* __restrict__ out, int write_out)
{
    __shared__ float Msh[NMON * CP];      // 3024
    __shared__ float phi_sh[NMON * 32];   // 4032
    __shared__ float cy_sh[32 * 25];      // conv-y result (+inv slots)
    __shared__ float blv_sh[32 * 25];
    __shared__ float mp_sh[32 * CP];
    __shared__ float q_sh[32 * CP];
    __shared__ float wsh[1386 + 63];
    const int tid = threadIdx.x;
    const int px0 = blockIdx.x * 32;
    const int i0 = px0 / IMW;             // block-uniform row (96 = 3*32)

    for (int idx = tid; idx < NMON * CP; idx += 256) {
        const int mm = idx / CP, c = idx % CP;
        Msh[idx] = (c < NCH) ? M[mm * NCH + c] : 0.f;
    }
    for (int idx = tid; idx < 441; idx += 256) {
        wsh[idx] = sp_w[idx]; wsh[441 + idx] = bl_w[idx]; wsh[882 + idx] = comp_w[idx];
    }
    if (tid < 21) {
        wsh[1323 + tid] = sp_b[tid]; wsh[1344 + tid] = bl_b[tid];
        wsh[1365 + tid] = comp_b[tid];
    }
    if (blockIdx.x < 11) {
        const int idx = blockIdx.x * 256 + tid;
        if (idx < 2772) Mnext[idx] = 0.f;
    }
    // phi tile [126][32]
    for (int idx = tid; idx < NMON * 8; idx += 256) {
        const int m = idx >> 3, g = idx & 7;
        *(float4*)(phi_sh + m * 32 + g * 4) =
            *(const float4*)(phi + (size_t)m * NPIX + px0 + g * 4);
    }
    // conv-y: 24*32 tasks (ch >= 22 idle)
    for (int task = tid; task < 24 * 32; task += 256) {
        const int ch = task >> 5, p = task & 31;
        if (ch < NCH) {
            const int n = px0 + p;
            const float* plane = sx + (size_t)ch * NPIX;
            float a = GW[0] * plane[n];
            #pragma unroll
            for (int d = 1; d <= RAD; d++) {
                const float t = (i0 - d >= 0) ? plane[n - d * IMW] : 0.f;
                const float b = (i0 + d < IMH) ? plane[n + d * IMW] : 0.f;
                a = fmaf(GW[d], t + b, a);
            }
            cy_sh[p * 25 + ch] = a;
        }
    }
    __syncthreads();

    // stage2: thread = (px, 3-channel group)
    {
        const int p = tid & 31, c0 = (tid >> 5) * 3;
        float a0 = 0.f, a1 = 0.f, a2 = 0.f;
        for (int mm = 0; mm < NMON; mm++) {
            const float ph = phi_sh[mm * 32 + p];
            const float* Mr = Msh + mm * CP + c0;
            a0 = fmaf(ph, Mr[0], a0);
            a1 = fmaf(ph, Mr[1], a1);
            a2 = fmaf(ph, Mr[2], a2);
        }
        if (c0 < NCH)     blv_sh[p * 25 + c0] = a0;
        if (c0 + 1 < NCH) blv_sh[p * 25 + c0 + 1] = a1;
        if (c0 + 2 < NCH) blv_sh[p * 25 + c0 + 2] = a2;
    }
    __syncthreads();

    // matmul1: mp = sp_b + bl_b + invS*(sp_w@cy) + invB*(bl_w@blv)
    for (int t = tid; t < 672; t += 256) {
        const int p = t & 31, o = t >> 5;
        const float* cyr = cy_sh + p * 25;
        const float* blr = blv_sh + p * 25;
        float dS = 0.f, dB = 0.f;
        #pragma unroll
        for (int c = 0; c < NC; c++) {
            dS = fmaf(wsh[o * NC + c], cyr[c], dS);
            dB = fmaf(wsh[441 + o * NC + c], blr[c], dB);
        }
        mp_sh[p * CP + o] = wsh[1323 + o] + wsh[1344 + o] +
                            dS / cyr[21] + dB / blr[21];
    }
    __syncthreads();

    // matmul2: q = u - (comp_w @ mp + comp_b)
    for (int t = tid; t < 672; t += 256) {
        const int p = t & 31, o = t >> 5;
        const float* mpr = mp_sh + p * CP;
        float d = wsh[1365 + o];
        #pragma unroll
        for (int c = 0; c < NC; c++) d = fmaf(wsh[882 + o * NC + c], mpr[c], d);
        q_sh[p * CP + o] = u_pm[(size_t)(px0 + p) * CP + o] - d;
    }
    __syncthreads();

    // softmax + writes, thread = pixel
    if (tid < 32) {
        const int n = px0 + tid;
        float q[NC];
        #pragma unroll
        for (int o = 0; o < NC; o++) q[o] = q_sh[tid * CP + o];
        float mx = q[0];
        #pragma unroll
        for (int o = 1; o < NC; o++) mx = fmaxf(mx, q[o]);
        float sum = 0.f;
        #pragma unroll
        for (int o = 0; o < NC; o++) { q[o] = __expf(q[o] - mx); sum += q[o]; }
        const float inv = 1.f / sum;
        #pragma unroll
        for (int o = 0; o < NC; o++) q[o] *= inv;

        float4* sp = (float4*)(s_pm + (size_t)n * CP);
        sp[0] = make_float4(q[0], q[1], q[2], q[3]);
        sp[1] = make_float4(q[4], q[5], q[6], q[7]);
        sp[2] = make_float4(q[8], q[9], q[10], q[11]);
        sp[3] = make_float4(q[12], q[13], q[14], q[15]);
        sp[4] = make_float4(q[16], q[17], q[18], q[19]);
        sp[5] = make_float4(q[20], 1.f, 0.f, 0.f);
        #pragma unroll
        for (int o = 0; o < NC; o++) s_cm[(size_t)o * NPIX + n] = q[o];
        s_cm[(size_t)21 * NPIX + n] = 1.f;
        if (write_out)
            #pragma unroll
            for (int o = 0; o < NC; o++) out[(size_t)o * NPIX + n] = q[o];
    }
}

extern "C" void kernel_launch(void* const* d_in, const int* in_sizes, int n_in,
                              void* d_out, int out_size, void* d_ws, size_t ws_size,
                              hipStream_t stream) {
    const float* img    = (const float*)d_in[0];
    const float* net_w  = (const float*)d_in[1];
    const float* net_b  = (const float*)d_in[2];
    const float* sp_w   = (const float*)d_in[3];
    const float* sp_b   = (const float*)d_in[4];
    const float* bl_w   = (const float*)d_in[5];
    const float* bl_b   = (const float*)d_in[6];
    const float* comp_w = (const float*)d_in[7];
    const float* comp_b = (const float*)d_in[8];

    float* u_pm = (float*)d_ws;                  // [NPIX][24]
    float* s_pm = u_pm + (size_t)NPIX * CP;      // [NPIX][24]
    float* s_cm = s_pm + (size_t)NPIX * CP;      // [22][NPIX]
    float* sx   = s_cm + (size_t)NCH * NPIX;     // [22][NPIX]
    float* phi  = sx + (size_t)NCH * NPIX;       // [126][NPIX]
    float* M    = phi + (size_t)NMON * NPIX;     // [2][MPAD]

    float* out = (float*)d_out;

    prep_kernel<<<dim3(144), dim3(64), 0, stream>>>(
        img, net_w, net_b, u_pm, s_pm, s_cm, phi, M);
    for (int it = 0; it < NITER; it++) {
        float* Mc = M + (it & 1) * MPAD;
        float* Mn = M + ((it + 1) & 1) * MPAD;
        k1_kernel<<<dim3(NMG * 36 + NCH * 36), dim3(256), 0, stream>>>(
            s_pm, s_cm, phi, sx, Mc);
        k2_kernel<<<dim3(288), dim3(256), 0, stream>>>(
            sx, phi, Mc, Mn, u_pm, sp_w, sp_b, bl_w, bl_b, comp_w, comp_b,
            s_pm, s_cm, out, it == NITER - 1 ? 1 : 0);
    }
}